// Round 2
// baseline (439.724 us; speedup 1.0000x reference)
//
#include <hip/hip_runtime.h>

// Problem constants (from reference setup_inputs)
#define BB 8
#define AA 100000
#define KK 80
#define MM 32
#define TILE 128            // anchors per block (r2: was 256 — grid quantization
                            // fix: 6256 blocks = 3.05 machine-rounds vs 1.53)
// ALPHA = 0.25, GAMMA = 2.0 baked in below.

// Per classification element:
//   x  = clip(c, 1e-4, 1-1e-4)            (x in [1e-4, 0.9999], always >= 0)
//   s  = log(1 + e^{-x}) = -log(p) = softplus(-x)
//   p  = 1/(1+e^{-x})
//   contribution = 0.25*(1-p)^2*s                    (targets != 0 path)
//                = 0.75*p^2*(x+s)                    (positive anchor, k != class)
__device__ __forceinline__ float cls_term(float c, int code, int k) {
    float x   = __builtin_amdgcn_fmed3f(c, 1e-4f, 1.0f - 1e-4f); // clamp, 1 op
    float em  = __expf(-x);
    float u   = 1.0f + em;
    float s   = __logf(u);
    float p   = __builtin_amdgcn_rcpf(u);   // smooth path only: 1-ulp rcp OK
    float omp = 1.0f - p;
    bool use2 = (code >= 0) && (k != code);
    return use2 ? (0.75f * p * p * (x + s)) : (0.25f * omp * omp * s);
}

// All-negative-anchor term: bit-identical to cls_term's use2==false result.
__device__ __forceinline__ float neg_term(float c) {
    float x   = __builtin_amdgcn_fmed3f(c, 1e-4f, 1.0f - 1e-4f);
    float em  = __expf(-x);
    float u   = 1.0f + em;
    float s   = __logf(u);
    float p   = __builtin_amdgcn_rcpf(u);
    float omp = 1.0f - p;
    return 0.25f * omp * omp * s;
}

__global__ __launch_bounds__(256)
void focal_main(const float* __restrict__ cls,
                const float* __restrict__ reg,
                const float* __restrict__ anc,
                const float* __restrict__ ann,
                double* __restrict__ cls_sum,
                float*  __restrict__ reg_sum,
                int*    __restrict__ num_pos)
{
    const int blk = blockIdx.x;          // anchor tile within image
    const int b   = blockIdx.y;          // image
    const int t   = threadIdx.x;
    const int a0  = blk * TILE;
    const int nA  = min(TILE, AA - a0);  // 32 for the last tile (781*128+32)
    const bool full = (nA == TILE);

    __shared__ float s_ann[MM * 5];
    __shared__ int   s_code[TILE];
    __shared__ float s_wred[4];          // one slot per wave (256/64)
    __shared__ int   s_wnp[4];
    __shared__ float s_wrg[4];

    // ann + anchor loads first: their waits are counted vmcnt(N), not drains.
    float annv = 0.0f;
    if (t < MM * 5) annv = ann[b * MM * 5 + t];
    const int ai = a0 + t;
    float4 av = make_float4(0.f, 0.f, 0.f, 0.f);
    if (t < nA) av = ((const float4*)anc)[ai];

    if (t < MM * 5) s_ann[t] = annv;
    __syncthreads();

    // ---- Phase 2 preload: ALL 10 float4 issued here so they fly during
    // phase-1's ~2k-cycle IoU compute. The phase-1->2 barrier's vmcnt drain
    // then lands after the latency is already covered. 40 VGPR payload.
    const float4* c4 = (const float4*)(cls + ((size_t)b * AA + (size_t)a0) * KK);
    float4 v[10];
    if (full) {
        #pragma unroll
        for (int j = 0; j < 10; ++j) v[j] = c4[j * 256 + t];
    }

    // ---- Phase 1: per-anchor IoU / argmax / positive flag / reg loss ----
    // Only t < nA (<=128) participate; waves 2-3 idle briefly (phase 1 is
    // ~15% of issue; total per-anchor work across the grid is unchanged).
    int   code     = -1;
    float reg_part = 0.0f;
    int   pos      = 0;
    if (t < nA) {
        const float ax1 = av.x, ay1 = av.y, ax2 = av.z, ay2 = av.w;
        float best = -2.0f;           // any real iou (>= -1) beats this
        int   bidx = 0;
        const float a_area = (ax2 - ax1) * (ay2 - ay1);
        #pragma unroll
        for (int m = 0; m < MM; ++m) {
            float bx1 = s_ann[m * 5 + 0], by1 = s_ann[m * 5 + 1];
            float bx2 = s_ann[m * 5 + 2], by2 = s_ann[m * 5 + 3];
            float lab = s_ann[m * 5 + 4];
            float area  = (bx2 - bx1) * (by2 - by1);
            float iw    = fmaxf(fminf(ax2, bx2) - fmaxf(ax1, bx1), 0.0f);
            float ih    = fmaxf(fminf(ay2, by2) - fmaxf(ay1, by1), 0.0f);
            float inter = iw * ih;
            float ua    = fmaxf(a_area + area - inter, 1e-8f);
            float iou   = inter / ua;            // IEEE div: match XLA exactly
            if (lab == -1.0f) iou = -1.0f;
            if (iou > best) { best = iou; bidx = m; }  // strict > = first-argmax
        }
        if (best >= 0.5f) {
            pos  = 1;
            code = (int)s_ann[bidx * 5 + 4];
            // smooth-L1 regression loss for this positive anchor
            float gx1 = s_ann[bidx * 5 + 0], gy1 = s_ann[bidx * 5 + 1];
            float gx2 = s_ann[bidx * 5 + 2], gy2 = s_ann[bidx * 5 + 3];
            float aw  = ax2 - ax1,  ah  = ay2 - ay1;
            float acx = ax1 + 0.5f * aw, acy = ay1 + 0.5f * ah;
            float gw  = gx2 - gx1,  gh  = gy2 - gy1;
            float gcx = gx1 + 0.5f * gw, gcy = gy1 + 0.5f * gh; // before clip!
            gw = fmaxf(gw, 1.0f); gh = fmaxf(gh, 1.0f);
            float tt0 = ((gcx - acx) / aw) / 0.1f;
            float tt1 = ((gcy - acy) / ah) / 0.1f;
            float tt2 = logf(gw / aw) / 0.2f;
            float tt3 = logf(gh / ah) / 0.2f;
            const float4 rv = ((const float4*)reg)[(size_t)b * AA + ai];
            float d0 = fabsf(tt0 - rv.x);
            float d1 = fabsf(tt1 - rv.y);
            float d2 = fabsf(tt2 - rv.z);
            float d3 = fabsf(tt3 - rv.w);
            const float th = 1.0f / 9.0f, hb = 0.5f / 9.0f;
            reg_part  = (d0 <= th ? 4.5f * d0 * d0 : d0 - hb)
                      + (d1 <= th ? 4.5f * d1 * d1 : d1 - hb)
                      + (d2 <= th ? 4.5f * d2 * d2 : d2 - hb)
                      + (d3 <= th ? 4.5f * d3 * d3 : d3 - hb);
        }
    }
    if (t < TILE) s_code[t] = code;      // t in [nA,TILE) writes -1 (tail tile)

    // wave-level aggregation of num_pos / reg_sum (no LDS atomics)
    {
        unsigned long long bal = __ballot(pos != 0);
        int wnp = __popcll(bal);
        float wrg = reg_part;
        #pragma unroll
        for (int off = 32; off > 0; off >>= 1) wrg += __shfl_down(wrg, off, 64);
        int wid  = t >> 6;
        int lane = t & 63;
        if (lane == 0) { s_wnp[wid] = wnp; s_wrg[wid] = wrg; }
    }
    __syncthreads();   // drains the v[] preloads — phase 1 covered the latency
    if (t == 0) {
        int   np = s_wnp[0] + s_wnp[1] + s_wnp[2] + s_wnp[3];
        float rg = s_wrg[0] + s_wrg[1] + s_wrg[2] + s_wrg[3];
        if (np != 0)  atomicAdd(&num_pos[b], np);
        if (rg != 0.f) atomicAdd(&reg_sum[b], rg);
    }

    // ---- Phase 2: coalesced float4 sweep of this tile's 128x80 cls rows ----
    float part = 0.0f;
    auto process = [&](const float4 vv, int idx4) {
        unsigned e  = (unsigned)idx4 * 4u;     // element offset; e%4==0, 80%4==0
        unsigned al = e / 80u;                 // local anchor (0..127)
        unsigned k0 = e - al * 80u;            // class index of vv.x
        int ca = s_code[al];
        // Wave-uniform branch: positives ~<1% of anchors, so ~85% of
        // wave-iterations are all-negative — term1-only path, bit-identical.
        if (__ballot(ca >= 0) == 0ULL) {
            part += neg_term(vv.x);
            part += neg_term(vv.y);
            part += neg_term(vv.z);
            part += neg_term(vv.w);
        } else {
            part += cls_term(vv.x, ca, (int)k0);
            part += cls_term(vv.y, ca, (int)k0 + 1);
            part += cls_term(vv.z, ca, (int)k0 + 2);
            part += cls_term(vv.w, ca, (int)k0 + 3);
        }
    };

    if (full) {
        #pragma unroll
        for (int j = 0; j < 10; ++j) process(v[j], j * 256 + t);
    } else {
        // tail tile (blk==781, nA==32): guarded loads, 8 of 6256 blocks
        const int limit4 = nA * (KK / 4);
        #pragma unroll 4
        for (int j = 0; j < 10; ++j) {
            int idx4 = j * 256 + t;
            if (idx4 < limit4) { float4 vv = c4[idx4]; process(vv, idx4); }
        }
    }

    // wave shuffle reduce, then 4 partials through LDS, one atomic per block
    #pragma unroll
    for (int off = 32; off > 0; off >>= 1) part += __shfl_down(part, off, 64);
    if ((t & 63) == 0) s_wred[t >> 6] = part;
    __syncthreads();
    if (t == 0) {
        float tot = s_wred[0] + s_wred[1] + s_wred[2] + s_wred[3];
        atomicAdd(&cls_sum[b], (double)tot);
    }
}

__global__ void focal_final(const float* __restrict__ ann,
                            const double* __restrict__ cls_sum,
                            const float* __restrict__ reg_sum,
                            const int* __restrict__ num_pos,
                            float* __restrict__ out)
{
    __shared__ float s_c[BB], s_r[BB];
    int t = threadIdx.x;
    if (t < BB) {
        bool has = false;
        for (int m = 0; m < MM; ++m)
            has |= (ann[t * MM * 5 + m * 5 + 4] != -1.0f);
        float np   = (float)num_pos[t];
        float ctot = (float)cls_sum[t] / fmaxf(np, 0.01f);
        float rtot = (np > 0.0f) ? (reg_sum[t] / fmaxf(np * 4.0f, 1.0f)) : 0.0f;
        s_c[t] = has ? ctot : 0.0f;
        s_r[t] = has ? rtot : 0.0f;
    }
    __syncthreads();
    if (t == 0) {
        float c = 0.0f, r = 0.0f;
        for (int b = 0; b < BB; ++b) { c += s_c[b]; r += s_r[b]; }
        out[0] = c / (float)BB;
        out[1] = r / (float)BB;
    }
}

extern "C" void kernel_launch(void* const* d_in, const int* in_sizes, int n_in,
                              void* d_out, int out_size, void* d_ws, size_t ws_size,
                              hipStream_t stream) {
    const float* cls = (const float*)d_in[0];   // (B, A, K)
    const float* reg = (const float*)d_in[1];   // (B, A, 4)
    const float* anc = (const float*)d_in[2];   // (1, A, 4)
    const float* ann = (const float*)d_in[3];   // (B, M, 5)
    float* out = (float*)d_out;                 // [mean_cls, mean_reg]

    double* cls_sum = (double*)d_ws;
    float*  reg_sum = (float*)((char*)d_ws + BB * sizeof(double));
    int*    num_pos = (int*)((char*)d_ws + BB * sizeof(double) + BB * sizeof(float));
    size_t  acc_bytes = BB * sizeof(double) + BB * sizeof(float) + BB * sizeof(int);

    (void)hipMemsetAsync(d_ws, 0, acc_bytes, stream);   // graph-capture-safe

    dim3 grid((AA + TILE - 1) / TILE, BB);        // (782, 8)
    focal_main<<<grid, 256, 0, stream>>>(cls, reg, anc, ann,
                                         cls_sum, reg_sum, num_pos);
    focal_final<<<1, 64, 0, stream>>>(ann, cls_sum, reg_sum, num_pos, out);
}

// Round 4
// 379.441 us; speedup vs baseline: 1.1589x; 1.1589x over previous
//
#include <hip/hip_runtime.h>

// Problem constants (from reference setup_inputs)
#define BB 8
#define AA 100000
#define KK 80
#define MM 32
#define TILE 128            // anchors per block
#define NBLK 782            // (AA + TILE - 1) / TILE
#define NBLK_P 784          // padded stride for partial arrays
// ALPHA = 0.25, GAMMA = 2.0 baked in below.
//
// r3 (resubmit after container flake): NO GLOBAL ATOMICS. r2 counters showed
// WRITE_SIZE == blocks*64B and dur == blocks*30ns: the per-block f64
// atomicAdd to a single cache line (cls_sum[0..7] = one 64B line) is a
// serialized far-atomic RMW chain that was the whole critical path. Each
// block now writes unique partial slots; focal_final tree-reduces in f64.

__device__ __forceinline__ float cls_term(float c, int code, int k) {
    float x   = __builtin_amdgcn_fmed3f(c, 1e-4f, 1.0f - 1e-4f); // clamp, 1 op
    float em  = __expf(-x);
    float u   = 1.0f + em;
    float s   = __logf(u);
    float p   = __builtin_amdgcn_rcpf(u);   // smooth path only: 1-ulp rcp OK
    float omp = 1.0f - p;
    bool use2 = (code >= 0) && (k != code);
    return use2 ? (0.75f * p * p * (x + s)) : (0.25f * omp * omp * s);
}

// All-negative-anchor term: bit-identical to cls_term's use2==false result.
__device__ __forceinline__ float neg_term(float c) {
    float x   = __builtin_amdgcn_fmed3f(c, 1e-4f, 1.0f - 1e-4f);
    float em  = __expf(-x);
    float u   = 1.0f + em;
    float s   = __logf(u);
    float p   = __builtin_amdgcn_rcpf(u);
    float omp = 1.0f - p;
    return 0.25f * omp * omp * s;
}

__global__ __launch_bounds__(256)
void focal_main(const float* __restrict__ cls,
                const float* __restrict__ reg,
                const float* __restrict__ anc,
                const float* __restrict__ ann,
                float* __restrict__ cls_part,   // [BB][NBLK_P]
                float* __restrict__ reg_part_g, // [BB][NBLK_P]
                int*   __restrict__ np_part)    // [BB][NBLK_P]
{
    const int blk = blockIdx.x;          // anchor tile within image
    const int b   = blockIdx.y;          // image
    const int t   = threadIdx.x;
    const int a0  = blk * TILE;
    const int nA  = min(TILE, AA - a0);  // 32 for the last tile
    const bool full = (nA == TILE);

    __shared__ float s_ann[MM * 5];
    __shared__ int   s_code[TILE];
    __shared__ float s_wred[4];          // one slot per wave (256/64)
    __shared__ int   s_wnp[4];
    __shared__ float s_wrg[4];

    // ann + anchor loads first: their waits are counted vmcnt(N), not drains.
    float annv = 0.0f;
    if (t < MM * 5) annv = ann[b * MM * 5 + t];
    const int ai = a0 + t;
    float4 av = make_float4(0.f, 0.f, 0.f, 0.f);
    if (t < nA) av = ((const float4*)anc)[ai];

    if (t < MM * 5) s_ann[t] = annv;
    __syncthreads();

    // ---- Phase 2 preload: all 10 float4 issued here so they fly during
    // phase-1's IoU compute; the phase-1->2 barrier drain lands after the
    // latency is already covered.
    const float4* c4 = (const float4*)(cls + ((size_t)b * AA + (size_t)a0) * KK);
    float4 v[10];
    if (full) {
        #pragma unroll
        for (int j = 0; j < 10; ++j) v[j] = c4[j * 256 + t];
    }

    // ---- Phase 1: per-anchor IoU / argmax / positive flag / reg loss ----
    int   code     = -1;
    float reg_part = 0.0f;
    int   pos      = 0;
    if (t < nA) {
        const float ax1 = av.x, ay1 = av.y, ax2 = av.z, ay2 = av.w;
        float best = -2.0f;           // any real iou (>= -1) beats this
        int   bidx = 0;
        const float a_area = (ax2 - ax1) * (ay2 - ay1);
        #pragma unroll
        for (int m = 0; m < MM; ++m) {
            float bx1 = s_ann[m * 5 + 0], by1 = s_ann[m * 5 + 1];
            float bx2 = s_ann[m * 5 + 2], by2 = s_ann[m * 5 + 3];
            float lab = s_ann[m * 5 + 4];
            float area  = (bx2 - bx1) * (by2 - by1);
            float iw    = fmaxf(fminf(ax2, bx2) - fmaxf(ax1, bx1), 0.0f);
            float ih    = fmaxf(fminf(ay2, by2) - fmaxf(ay1, by1), 0.0f);
            float inter = iw * ih;
            float ua    = fmaxf(a_area + area - inter, 1e-8f);
            float iou   = inter / ua;            // IEEE div: match XLA exactly
            if (lab == -1.0f) iou = -1.0f;
            if (iou > best) { best = iou; bidx = m; }  // strict > = first-argmax
        }
        if (best >= 0.5f) {
            pos  = 1;
            code = (int)s_ann[bidx * 5 + 4];
            // smooth-L1 regression loss for this positive anchor
            float gx1 = s_ann[bidx * 5 + 0], gy1 = s_ann[bidx * 5 + 1];
            float gx2 = s_ann[bidx * 5 + 2], gy2 = s_ann[bidx * 5 + 3];
            float aw  = ax2 - ax1,  ah  = ay2 - ay1;
            float acx = ax1 + 0.5f * aw, acy = ay1 + 0.5f * ah;
            float gw  = gx2 - gx1,  gh  = gy2 - gy1;
            float gcx = gx1 + 0.5f * gw, gcy = gy1 + 0.5f * gh; // before clip!
            gw = fmaxf(gw, 1.0f); gh = fmaxf(gh, 1.0f);
            float tt0 = ((gcx - acx) / aw) / 0.1f;
            float tt1 = ((gcy - acy) / ah) / 0.1f;
            float tt2 = logf(gw / aw) / 0.2f;
            float tt3 = logf(gh / ah) / 0.2f;
            const float4 rv = ((const float4*)reg)[(size_t)b * AA + ai];
            float d0 = fabsf(tt0 - rv.x);
            float d1 = fabsf(tt1 - rv.y);
            float d2 = fabsf(tt2 - rv.z);
            float d3 = fabsf(tt3 - rv.w);
            const float th = 1.0f / 9.0f, hb = 0.5f / 9.0f;
            reg_part  = (d0 <= th ? 4.5f * d0 * d0 : d0 - hb)
                      + (d1 <= th ? 4.5f * d1 * d1 : d1 - hb)
                      + (d2 <= th ? 4.5f * d2 * d2 : d2 - hb)
                      + (d3 <= th ? 4.5f * d3 * d3 : d3 - hb);
        }
    }
    if (t < TILE) s_code[t] = code;      // t in [nA,TILE) writes -1 (tail tile)

    // wave-level aggregation of num_pos / reg_sum (no atomics anywhere)
    {
        unsigned long long bal = __ballot(pos != 0);
        int wnp = __popcll(bal);
        float wrg = reg_part;
        #pragma unroll
        for (int off = 32; off > 0; off >>= 1) wrg += __shfl_down(wrg, off, 64);
        int wid  = t >> 6;
        int lane = t & 63;
        if (lane == 0) { s_wnp[wid] = wnp; s_wrg[wid] = wrg; }
    }
    __syncthreads();   // drains the v[] preloads — phase 1 covered the latency
    if (t == 0) {
        int   np = s_wnp[0] + s_wnp[1] + s_wnp[2] + s_wnp[3];
        float rg = s_wrg[0] + s_wrg[1] + s_wrg[2] + s_wrg[3];
        np_part   [b * NBLK_P + blk] = np;   // unique slot: no contention,
        reg_part_g[b * NBLK_P + blk] = rg;   // fire-and-forget stores
    }

    // ---- Phase 2: coalesced float4 sweep of this tile's 128x80 cls rows ----
    float part = 0.0f;
    auto process = [&](const float4 vv, int idx4) {
        unsigned e  = (unsigned)idx4 * 4u;     // element offset; e%4==0, 80%4==0
        unsigned al = e / 80u;                 // local anchor (0..127)
        unsigned k0 = e - al * 80u;            // class index of vv.x
        int ca = s_code[al];
        // Wave-uniform branch: ~85%+ of wave-iterations are all-negative —
        // term1-only path, bit-identical to the cndmask result.
        if (__ballot(ca >= 0) == 0ULL) {
            part += neg_term(vv.x);
            part += neg_term(vv.y);
            part += neg_term(vv.z);
            part += neg_term(vv.w);
        } else {
            part += cls_term(vv.x, ca, (int)k0);
            part += cls_term(vv.y, ca, (int)k0 + 1);
            part += cls_term(vv.z, ca, (int)k0 + 2);
            part += cls_term(vv.w, ca, (int)k0 + 3);
        }
    };

    if (full) {
        #pragma unroll
        for (int j = 0; j < 10; ++j) process(v[j], j * 256 + t);
    } else {
        // tail tile (blk==781, nA==32): guarded loads, 8 of 6256 blocks
        const int limit4 = nA * (KK / 4);
        #pragma unroll 4
        for (int j = 0; j < 10; ++j) {
            int idx4 = j * 256 + t;
            if (idx4 < limit4) { float4 vv = c4[idx4]; process(vv, idx4); }
        }
    }

    // wave shuffle reduce, 4 partials through LDS, one plain store per block
    #pragma unroll
    for (int off = 32; off > 0; off >>= 1) part += __shfl_down(part, off, 64);
    if ((t & 63) == 0) s_wred[t >> 6] = part;
    __syncthreads();
    if (t == 0) {
        float tot = s_wred[0] + s_wred[1] + s_wred[2] + s_wred[3];
        cls_part[b * NBLK_P + blk] = tot;
    }
}

__global__ __launch_bounds__(256)
void focal_final(const float* __restrict__ ann,
                 const float* __restrict__ cls_part,
                 const float* __restrict__ reg_part,
                 const int*   __restrict__ np_part,
                 float* __restrict__ out)
{
    const int t    = threadIdx.x;
    const int lane = t & 63, wid = t >> 6;
    __shared__ double sd[4];
    __shared__ float  sf[4];
    __shared__ int    si[4];
    __shared__ float  s_c[BB], s_r[BB];

    for (int b = 0; b < BB; ++b) {
        double cd = 0.0; float rf = 0.0f; int np = 0;
        for (int j = t; j < NBLK; j += 256) {
            cd += (double)cls_part[b * NBLK_P + j];
            rf += reg_part[b * NBLK_P + j];
            np += np_part [b * NBLK_P + j];
        }
        #pragma unroll
        for (int off = 32; off > 0; off >>= 1) {
            cd += __shfl_down(cd, off, 64);
            rf += __shfl_down(rf, off, 64);
            np += __shfl_down(np, off, 64);
        }
        if (lane == 0) { sd[wid] = cd; sf[wid] = rf; si[wid] = np; }
        __syncthreads();
        if (t == 0) {
            double cdt = sd[0] + sd[1] + sd[2] + sd[3];
            float  rft = sf[0] + sf[1] + sf[2] + sf[3];
            int    npt = si[0] + si[1] + si[2] + si[3];
            bool has = false;
            for (int m = 0; m < MM; ++m)
                has |= (ann[b * MM * 5 + m * 5 + 4] != -1.0f);
            float npf  = (float)npt;
            float ctot = (float)cdt / fmaxf(npf, 0.01f);
            float rtot = (npt > 0) ? (rft / fmaxf(npf * 4.0f, 1.0f)) : 0.0f;
            s_c[b] = has ? ctot : 0.0f;
            s_r[b] = has ? rtot : 0.0f;
        }
        __syncthreads();   // protects sd/sf/si reuse for next image
    }
    if (t == 0) {
        float c = 0.0f, r = 0.0f;
        for (int b = 0; b < BB; ++b) { c += s_c[b]; r += s_r[b]; }
        out[0] = c / (float)BB;
        out[1] = r / (float)BB;
    }
}

extern "C" void kernel_launch(void* const* d_in, const int* in_sizes, int n_in,
                              void* d_out, int out_size, void* d_ws, size_t ws_size,
                              hipStream_t stream) {
    const float* cls = (const float*)d_in[0];   // (B, A, K)
    const float* reg = (const float*)d_in[1];   // (B, A, 4)
    const float* anc = (const float*)d_in[2];   // (1, A, 4)
    const float* ann = (const float*)d_in[3];   // (B, M, 5)
    float* out = (float*)d_out;                 // [mean_cls, mean_reg]

    // Workspace: per-block partials, every slot written unconditionally by
    // its block -> no memset needed (one fewer dispatch in the graph).
    float* cls_part = (float*)d_ws;
    float* reg_part = cls_part + BB * NBLK_P;
    int*   np_part  = (int*)(reg_part + BB * NBLK_P);

    dim3 grid(NBLK, BB);                          // (782, 8)
    focal_main<<<grid, 256, 0, stream>>>(cls, reg, anc, ann,
                                         cls_part, reg_part, np_part);
    focal_final<<<1, 256, 0, stream>>>(ann, cls_part, reg_part, np_part, out);
}